// Round 16
// baseline (340.979 us; speedup 1.0000x reference)
//
#include <hip/hip_runtime.h>
#include <hip/hip_bf16.h>

// GraphNeuralAssociator: GCN(3 layers, fp32) + all-pairs edge MLP.
// Edge MLP layer 1 factorized: h1(i,j) = relu(Amat[i] + Bmat[j]).
// Layer 2 (68.6 GF) = bf16 MFMA 16x16x32, fp32 accum; layer 3 + sigmoid fused.
// v16: (a) edge build_h1 uses __float2bfloat16 casts (compiler fuses to
// v_cvt_pk_bf16_f32; manual bit-f2bf blocked it - m240). (b) parity-staggered
// build: odd waves slab3->build, even waves build->slab3 (independent bufs)
// -> cross-wave MFMA/VALU overlap during build. (c) gemm_ks4 gains z-dual +
// bias; used for P5 (full GPU 4 waves/SIMD) and P6.

#define NN 512
#define FF 256
#define HH 512

typedef __attribute__((ext_vector_type(8))) short s8v;   // 8 x bf16 bits
typedef __attribute__((ext_vector_type(4))) float f4v;   // MFMA acc

__device__ __forceinline__ ushort f2bf(float f) {
  // compiler-fusible RNE cast (pairs fuse to v_cvt_pk_bf16_f32 - m240)
  union { __hip_bfloat16 h; ushort u; } b;
  b.h = __float2bfloat16(f);
  return b.u;
}

// ---------------- device tile GEMM: 16x64 tile, BK=64 (256 thr) ------------
template <bool RELU>
__device__ __forceinline__ void gemm_tile64(
    int m0, int n0, int K,
    const float* __restrict__ A, int lda,
    const float* __restrict__ B, int ldb,
    const float* __restrict__ bias,
    const float* __restrict__ add, int ldadd,
    float* __restrict__ C, int ldc, int tid)
{
  __shared__ float As[64][18];  // [k][m]
  __shared__ float Bs[64][68];  // [k][n]
  float4 acc = {0.f, 0.f, 0.f, 0.f};
  const int ty = tid >> 4, tx = tid & 15;

  const int am = tid >> 4;      // A row 0..15
  const int ak = tid & 15;      // k float4 index (16 x 4 = 64 k)
  const int bk = tid >> 4;      // B rows bk + 16r, r=0..3
  const int bn = tid & 15;      // col float4 index

  float4 pa = *(const float4*)&A[(m0 + am) * lda + ak * 4];
  float4 pb0 = *(const float4*)&B[bk * ldb + n0 + bn * 4];
  float4 pb1 = *(const float4*)&B[(bk + 16) * ldb + n0 + bn * 4];
  float4 pb2 = *(const float4*)&B[(bk + 32) * ldb + n0 + bn * 4];
  float4 pb3 = *(const float4*)&B[(bk + 48) * ldb + n0 + bn * 4];

  for (int k0 = 0; k0 < K; k0 += 64) {
    As[ak * 4 + 0][am] = pa.x;
    As[ak * 4 + 1][am] = pa.y;
    As[ak * 4 + 2][am] = pa.z;
    As[ak * 4 + 3][am] = pa.w;
    *(float4*)&Bs[bk][bn * 4] = pb0;
    *(float4*)&Bs[bk + 16][bn * 4] = pb1;
    *(float4*)&Bs[bk + 32][bn * 4] = pb2;
    *(float4*)&Bs[bk + 48][bn * 4] = pb3;
    __syncthreads();
    if (k0 + 64 < K) {
      pa = *(const float4*)&A[(m0 + am) * lda + k0 + 64 + ak * 4];
      pb0 = *(const float4*)&B[(k0 + 64 + bk) * ldb + n0 + bn * 4];
      pb1 = *(const float4*)&B[(k0 + 80 + bk) * ldb + n0 + bn * 4];
      pb2 = *(const float4*)&B[(k0 + 96 + bk) * ldb + n0 + bn * 4];
      pb3 = *(const float4*)&B[(k0 + 112 + bk) * ldb + n0 + bn * 4];
    }
#pragma unroll
    for (int k = 0; k < 64; ++k) {
      float a = As[k][ty];
      float4 b = *(const float4*)&Bs[k][tx * 4];
      acc.x += a * b.x; acc.y += a * b.y; acc.z += a * b.z; acc.w += a * b.w;
    }
    __syncthreads();
  }

  int m = m0 + ty;
  float4 v = acc;
  if (bias) {
    float4 bv = *(const float4*)&bias[n0 + tx * 4];
    v.x += bv.x; v.y += bv.y; v.z += bv.z; v.w += bv.w;
  }
  if (add) {
    float4 d = *(const float4*)&add[m * ldadd + n0 + tx * 4];
    v.x += d.x; v.y += d.y; v.z += d.z; v.w += d.w;
  }
  if (RELU) {
    v.x = fmaxf(v.x, 0.f); v.y = fmaxf(v.y, 0.f);
    v.z = fmaxf(v.z, 0.f); v.w = fmaxf(v.w, 0.f);
  }
  *(float4*)&C[m * ldc + n0 + tx * 4] = v;
}

// ---------------- K-split GEMM: 512 thr, 16x64 tile, halves split K --------
template <bool RELU>
__global__ __launch_bounds__(512)
void gemm_ks(int K,
             const float* __restrict__ A, int lda,
             const float* __restrict__ B0, const float* __restrict__ B1, int ldb,
             const float* __restrict__ bias0, const float* __restrict__ bias1,
             const float* __restrict__ add0, const float* __restrict__ add1, int ldadd,
             float* __restrict__ C0, float* __restrict__ C1, int ldc)
{
  const float* B = blockIdx.z ? B1 : B0;
  const float* bias = blockIdx.z ? bias1 : bias0;
  const float* add = blockIdx.z ? add1 : add0;
  float* C = blockIdx.z ? C1 : C0;
  const int n0 = blockIdx.x * 64;
  const int m0 = blockIdx.y * 16;
  const int tid = threadIdx.x;
  const int half = tid >> 8;
  const int t = tid & 255;
  const int ty = t >> 4, tx = t & 15;

  __shared__ float As[2][64][18];
  __shared__ float Bs[2][64][68];
  __shared__ float red[16][68];

  float4 acc = {0.f, 0.f, 0.f, 0.f};
  const int am = t >> 4, ak = t & 15;
  const int bk = t >> 4, bn = t & 15;
  const int Kh = K >> 1;
  const int kb = half * Kh;

  float4 pa = *(const float4*)&A[(m0 + am) * lda + kb + ak * 4];
  float4 pb0 = *(const float4*)&B[(kb + bk) * ldb + n0 + bn * 4];
  float4 pb1 = *(const float4*)&B[(kb + bk + 16) * ldb + n0 + bn * 4];
  float4 pb2 = *(const float4*)&B[(kb + bk + 32) * ldb + n0 + bn * 4];
  float4 pb3 = *(const float4*)&B[(kb + bk + 48) * ldb + n0 + bn * 4];

  for (int k0 = 0; k0 < Kh; k0 += 64) {
    As[half][ak * 4 + 0][am] = pa.x;
    As[half][ak * 4 + 1][am] = pa.y;
    As[half][ak * 4 + 2][am] = pa.z;
    As[half][ak * 4 + 3][am] = pa.w;
    *(float4*)&Bs[half][bk][bn * 4] = pb0;
    *(float4*)&Bs[half][bk + 16][bn * 4] = pb1;
    *(float4*)&Bs[half][bk + 32][bn * 4] = pb2;
    *(float4*)&Bs[half][bk + 48][bn * 4] = pb3;
    __syncthreads();
    if (k0 + 64 < Kh) {
      pa = *(const float4*)&A[(m0 + am) * lda + kb + k0 + 64 + ak * 4];
      pb0 = *(const float4*)&B[(kb + k0 + 64 + bk) * ldb + n0 + bn * 4];
      pb1 = *(const float4*)&B[(kb + k0 + 80 + bk) * ldb + n0 + bn * 4];
      pb2 = *(const float4*)&B[(kb + k0 + 96 + bk) * ldb + n0 + bn * 4];
      pb3 = *(const float4*)&B[(kb + k0 + 112 + bk) * ldb + n0 + bn * 4];
    }
#pragma unroll
    for (int k = 0; k < 64; ++k) {
      float a = As[half][k][ty];
      float4 b = *(const float4*)&Bs[half][k][tx * 4];
      acc.x += a * b.x; acc.y += a * b.y; acc.z += a * b.z; acc.w += a * b.w;
    }
    __syncthreads();
  }

  if (half) *(float4*)&red[ty][tx * 4] = acc;
  __syncthreads();
  if (!half) {
    float4 r = *(const float4*)&red[ty][tx * 4];
    float4 v = acc;
    v.x += r.x; v.y += r.y; v.z += r.z; v.w += r.w;
    int m = m0 + ty;
    if (bias) {
      float4 bv = *(const float4*)&bias[n0 + tx * 4];
      v.x += bv.x; v.y += bv.y; v.z += bv.z; v.w += bv.w;
    }
    if (add) {
      float4 d = *(const float4*)&add[m * ldadd + n0 + tx * 4];
      v.x += d.x; v.y += d.y; v.z += d.z; v.w += d.w;
    }
    if (RELU) {
      v.x = fmaxf(v.x, 0.f); v.y = fmaxf(v.y, 0.f);
      v.z = fmaxf(v.z, 0.f); v.w = fmaxf(v.w, 0.f);
    }
    *(float4*)&C[m * ldc + n0 + tx * 4] = v;
  }
}

// ---------------- 4-way K-split GEMM: 1024 thr, 16x64 tile, z-dual ---------
// quarter q covers k in [q*K/4, (q+1)*K/4); 16 waves = 4/SIMD at 1 block/CU.
template <bool RELU>
__global__ __launch_bounds__(1024)
void gemm_ks4(int K,
              const float* __restrict__ A, int lda,
              const float* __restrict__ B0, const float* __restrict__ B1, int ldb,
              const float* __restrict__ bias0, const float* __restrict__ bias1,
              const float* __restrict__ add0, const float* __restrict__ add1, int ldadd,
              float* __restrict__ C0, float* __restrict__ C1, int ldc)
{
  const float* B = blockIdx.z ? B1 : B0;
  const float* bias = blockIdx.z ? bias1 : bias0;
  const float* add = blockIdx.z ? add1 : add0;
  float* C = blockIdx.z ? C1 : C0;
  const int n0 = blockIdx.x * 64;
  const int m0 = blockIdx.y * 16;
  const int tid = threadIdx.x;
  const int q = tid >> 8;         // 0..3
  const int t = tid & 255;
  const int ty = t >> 4, tx = t & 15;

  __shared__ float As[4][64][18];   // 18.0 KB
  __shared__ float Bs[4][64][68];   // 68.0 KB
  __shared__ float red[3][16][68];  // 12.75 KB

  float4 acc = {0.f, 0.f, 0.f, 0.f};
  const int am = ty, ak = tx;
  const int bk = ty, bn = tx;
  const int Kq = K >> 2;
  const int kb = q * Kq;

  float4 pa = *(const float4*)&A[(m0 + am) * lda + kb + ak * 4];
  float4 pb0 = *(const float4*)&B[(kb + bk) * ldb + n0 + bn * 4];
  float4 pb1 = *(const float4*)&B[(kb + bk + 16) * ldb + n0 + bn * 4];
  float4 pb2 = *(const float4*)&B[(kb + bk + 32) * ldb + n0 + bn * 4];
  float4 pb3 = *(const float4*)&B[(kb + bk + 48) * ldb + n0 + bn * 4];

  for (int k0 = 0; k0 < Kq; k0 += 64) {
    As[q][ak * 4 + 0][am] = pa.x;
    As[q][ak * 4 + 1][am] = pa.y;
    As[q][ak * 4 + 2][am] = pa.z;
    As[q][ak * 4 + 3][am] = pa.w;
    *(float4*)&Bs[q][bk][bn * 4] = pb0;
    *(float4*)&Bs[q][bk + 16][bn * 4] = pb1;
    *(float4*)&Bs[q][bk + 32][bn * 4] = pb2;
    *(float4*)&Bs[q][bk + 48][bn * 4] = pb3;
    __syncthreads();
    if (k0 + 64 < Kq) {
      pa = *(const float4*)&A[(m0 + am) * lda + kb + k0 + 64 + ak * 4];
      pb0 = *(const float4*)&B[(kb + k0 + 64 + bk) * ldb + n0 + bn * 4];
      pb1 = *(const float4*)&B[(kb + k0 + 80 + bk) * ldb + n0 + bn * 4];
      pb2 = *(const float4*)&B[(kb + k0 + 96 + bk) * ldb + n0 + bn * 4];
      pb3 = *(const float4*)&B[(kb + k0 + 112 + bk) * ldb + n0 + bn * 4];
    }
#pragma unroll
    for (int k = 0; k < 64; ++k) {
      float a = As[q][k][ty];
      float4 b = *(const float4*)&Bs[q][k][tx * 4];
      acc.x += a * b.x; acc.y += a * b.y; acc.z += a * b.z; acc.w += a * b.w;
    }
    __syncthreads();
  }

  if (q) *(float4*)&red[q - 1][ty][tx * 4] = acc;
  __syncthreads();
  if (!q) {
    float4 v = acc;
#pragma unroll
    for (int r = 0; r < 3; ++r) {
      float4 p = *(const float4*)&red[r][ty][tx * 4];
      v.x += p.x; v.y += p.y; v.z += p.z; v.w += p.w;
    }
    int m = m0 + ty;
    if (bias) {
      float4 bv = *(const float4*)&bias[n0 + tx * 4];
      v.x += bv.x; v.y += bv.y; v.z += bv.z; v.w += bv.w;
    }
    if (add) {
      float4 d = *(const float4*)&add[m * ldadd + n0 + tx * 4];
      v.x += d.x; v.y += d.y; v.z += d.z; v.w += d.w;
    }
    if (RELU) {
      v.x = fmaxf(v.x, 0.f); v.y = fmaxf(v.y, 0.f);
      v.z = fmaxf(v.z, 0.f); v.w = fmaxf(v.w, 0.f);
    }
    *(float4*)&C[m * ldc + n0 + tx * 4] = v;
  }
}

// ---------------- launch 1: gemm1 (blocks 0..511) + rownorm (512..1023)
//                  + w2 pack (1024..1151) -----------------------------------
__global__ __launch_bounds__(256)
void prep_gemm1(const float* __restrict__ adj, float* __restrict__ adjn,
                const float* __restrict__ w2, ushort* __restrict__ w2t2,
                const float* __restrict__ node,
                const float* __restrict__ g1wl, const float* __restrict__ g1bl,
                const float* __restrict__ g1ws, const float* __restrict__ g1bs,
                float* __restrict__ Tb, float* __restrict__ Sb) {
  int b = blockIdx.x;
  int tid = threadIdx.x;
  if (b < 512) {
    int z = b >> 8, t = b & 255;
    int m0 = (t >> 3) * 16, n0 = (t & 7) * 64;
    gemm_tile64<false>(m0, n0, FF, node, FF, z ? g1ws : g1wl, HH,
                       z ? g1bs : g1bl, nullptr, 0, z ? Sb : Tb, HH, tid);
  } else if (b < 1024) {
    int row = b - 512;
    const float* r = adj + row * NN;
    float a0 = r[tid], a1 = r[tid + 256];
    float s = a0 + a1;
#pragma unroll
    for (int m = 1; m < 64; m <<= 1) s += __shfl_xor(s, m);
    __shared__ float wsum[4];
    if ((tid & 63) == 0) wsum[tid >> 6] = s;
    __syncthreads();
    float inv = 1.f / (wsum[0] + wsum[1] + wsum[2] + wsum[3] + 1e-8f);
    float* o = adjn + row * NN;
    o[tid] = a0 * inv;
    o[tid + 256] = a1 * inv;
  } else {
    // w2 -> bf16 pack: w2t2[(k>>5)*16384 + col*32 + (k&31)]
    int b2 = b - 1024;                      // 0..127
    int slab = b2 >> 3;                     // 16 slabs of 32 k
    int col = (b2 & 7) * 64 + (tid >> 2);
    int kq = tid & 3;                       // 8-k sub-block
    int k0 = slab * 32 + kq * 8;
    ushort tmp[8];
#pragma unroll
    for (int e = 0; e < 8; ++e) tmp[e] = f2bf(w2[(k0 + e) * HH + col]);
    ushort* dst = w2t2 + slab * 16384 + col * 32 + kq * 8;
    *(ushort4*)dst = *(ushort4*)tmp;
    *(ushort4*)(dst + 4) = *(ushort4*)&tmp[4];
  }
}

// ---------------- fused edge MLP ----------------
// v9 structure + (v16) compiler-fusible bf16 casts in build_h1 and
// parity-staggered build/slab3 for cross-wave MFMA/VALU overlap.
__global__ __launch_bounds__(512)
__attribute__((amdgpu_waves_per_eu(2, 2)))
void edge_mlp(const float* __restrict__ Amat, const float* __restrict__ Bmat,
              const ushort* __restrict__ w2t2,
              const float* __restrict__ b2, const float* __restrict__ w3,
              const float* __restrict__ b3,
              float* __restrict__ edges)
{
  __shared__ ushort h1s[2][128 * 128];   // 64 KB
  __shared__ float rowsv[2][24][128];    // 24 KB: rows 0-7 = A, 8-23 = B
  __shared__ float part[8][128];         // 4 KB

  // exact upper-triangle tile decode: tiles before col-block bj = bj^2+bj
  const int tb = (int)blockIdx.x;
  int bj = (int)((sqrtf(4.f * tb + 1.f) - 1.f) * 0.5f);
  while (bj * bj + bj > tb) --bj;
  while ((bj + 1) * (bj + 2) <= tb) ++bj;
  const int bi = tb - bj * bj - bj;

  const int tid = threadIdx.x;
  const int wid = tid >> 6;
  const int lane = tid & 63;
  const int l15 = lane & 15;
  const int lg = lane >> 4;

  const f4v zero = {0.f, 0.f, 0.f, 0.f};
  f4v acc[8][4];
#pragma unroll
  for (int mf = 0; mf < 8; ++mf)
#pragma unroll
    for (int nf = 0; nf < 4; ++nf) acc[mf][nf] = zero;

  // ---- row staging: 24 rows x 128 floats per chunk = 768 float4 elems ----
  const int r1 = tid >> 5, kc1 = tid & 31;          // elem tid (all threads)
  const int r2 = 16 + (tid >> 5);                   // elem 512+tid (tid<256)
  const float* src1base = (r1 < 8) ? (Amat + (bi * 8 + r1) * HH)
                                   : (Bmat + (bj * 16 + r1 - 8) * HH);
  const float* src2base = Bmat + (bj * 16 + r2 - 8) * HH;  // rows 16..23

  float4 ra, rb;
  auto issue_rows = [&](int ch) {  // global loads only (tiny: 1.5 f4/thread)
    ra = *(const float4*)(src1base + ch * 128 + kc1 * 4);
    if (tid < 256) rb = *(const float4*)(src2base + ch * 128 + kc1 * 4);
  };
  auto write_rows = [&](int buf) {  // ds_write (waits on the row loads)
    *(float4*)&rowsv[buf][r1][kc1 * 4] = ra;
    if (tid < 256) *(float4*)&rowsv[buf][r2][kc1 * 4] = rb;
  };
  // build h1 chunk from staged rows: h1[p][k]=relu(Arow[i(p)]+Brow[j(p)]) bf16
  auto build_h1 = [&](int buf) {
#pragma unroll
    for (int q = 0; q < 8; ++q) {
      int fidx = q * 512 + tid;
      int p = fidx >> 5;        // pair row 0..127
      int k4 = fidx & 31;       // float4 index within 128-k chunk
      float4 av = *(const float4*)&rowsv[buf][p >> 4][k4 * 4];
      float4 bv = *(const float4*)&rowsv[buf][8 + (p & 15)][k4 * 4];
      ushort4 pk;
      pk.x = f2bf(fmaxf(av.x + bv.x, 0.f));
      pk.y = f2bf(fmaxf(av.y + bv.y, 0.f));
      pk.z = f2bf(fmaxf(av.z + bv.z, 0.f));
      pk.w = f2bf(fmaxf(av.w + bv.w, 0.f));
      int off = (p * 256 + k4 * 8) ^ ((p & 7) << 4);
      *(ushort4*)((char*)h1s[buf] + off) = pk;
    }
  };

  // lgkm-only barrier (no vmcnt drain; w2/row prefetch stays in flight)
  auto lgkm_barrier = [] {
    asm volatile("s_waitcnt lgkmcnt(0)" ::: "memory");
    __builtin_amdgcn_s_barrier();
  };

  // prologue: stage rows(0) -> rowsv[0], build h1s[0]
  issue_rows(0);
  write_rows(0);
  lgkm_barrier();           // rows visible block-wide
  build_h1(0);
  lgkm_barrier();           // h1s[0] ready

  // wave's w2 base: cols [64*wid ..), lane l15 col, lane-group lg k-offset
  const ushort* wbase = w2t2 + wid * 2048 + l15 * 32 + lg * 8;

  // rolling w2 prefetch (one 32-k slab ahead, across chunk boundaries)
  s8v nb0, nb1, nb2, nb3;
  nb0 = *(const s8v*)wbase;
  nb1 = *(const s8v*)(wbase + 512);
  nb2 = *(const s8v*)(wbase + 1024);
  nb3 = *(const s8v*)(wbase + 1536);

  // one 32-k slab: 8 ds_reads + 32 MFMAs, rolls w2 prefetch
  auto slab_step = [&](int cur, int slab) {
    s8v cb0 = nb0, cb1 = nb1, cb2 = nb2, cb3 = nb3;
    if (slab < 15) {
      const ushort* wb = wbase + (slab + 1) * 16384;
      nb0 = *(const s8v*)wb;
      nb1 = *(const s8v*)(wb + 512);
      nb2 = *(const s8v*)(wb + 1024);
      nb3 = *(const s8v*)(wb + 1536);
    }
    int ks = slab & 3;
    __builtin_amdgcn_s_setprio(1);
#pragma unroll
    for (int mf = 0; mf < 8; ++mf) {
      int p = mf * 16 + l15;
      int off = (p * 256 + ks * 64 + lg * 16) ^ ((p & 7) << 4);
      s8v a = *(const s8v*)((const char*)h1s[cur] + off);
      acc[mf][0] = __builtin_amdgcn_mfma_f32_16x16x32_bf16(a, cb0, acc[mf][0], 0, 0, 0);
      acc[mf][1] = __builtin_amdgcn_mfma_f32_16x16x32_bf16(a, cb1, acc[mf][1], 0, 0, 0);
      acc[mf][2] = __builtin_amdgcn_mfma_f32_16x16x32_bf16(a, cb2, acc[mf][2], 0, 0, 0);
      acc[mf][3] = __builtin_amdgcn_mfma_f32_16x16x32_bf16(a, cb3, acc[mf][3], 0, 0, 0);
    }
    __builtin_amdgcn_s_setprio(0);
  };

#pragma unroll
  for (int ch = 0; ch < 4; ++ch) {
    int cur = ch & 1;
    if (ch < 3) issue_rows(ch + 1);          // row loads fly under slabs 0-1
    slab_step(cur, ch * 4 + 0);
    slab_step(cur, ch * 4 + 1);
    if (ch < 3) write_rows(cur ^ 1);         // counted vmcnt (w2 loads younger)
    slab_step(cur, ch * 4 + 2);
    if (ch < 3) {
      lgkm_barrier();                        // rows visible block-wide
      // parity stagger: build (VALU) and slab3 (MFMA) touch different
      // buffers; alternate order per wave so SIMD-mates overlap pipes.
      if (wid & 1) {
        slab_step(cur, ch * 4 + 3);
        build_h1(cur ^ 1);
      } else {
        build_h1(cur ^ 1);
        slab_step(cur, ch * 4 + 3);
      }
      lgkm_barrier();                        // h1s[cur^1] ready
    } else {
      slab_step(cur, ch * 4 + 3);
    }
  }

  // epilogue: h2 = relu(acc+b2); partial = h2 . w3 over this wave's 64 cols
  float bb[4], ww[4];
#pragma unroll
  for (int nf = 0; nf < 4; ++nf) {
    int col = wid * 64 + nf * 16 + l15;
    bb[nf] = b2[col];
    ww[nf] = w3[col];
  }
#pragma unroll
  for (int mf = 0; mf < 8; ++mf) {
    float ps[4];
#pragma unroll
    for (int e = 0; e < 4; ++e) {
      ps[e] = fmaxf(acc[mf][0][e] + bb[0], 0.f) * ww[0] +
              fmaxf(acc[mf][1][e] + bb[1], 0.f) * ww[1] +
              fmaxf(acc[mf][2][e] + bb[2], 0.f) * ww[2] +
              fmaxf(acc[mf][3][e] + bb[3], 0.f) * ww[3];
    }
#pragma unroll
    for (int m = 1; m < 16; m <<= 1) {
#pragma unroll
      for (int e = 0; e < 4; ++e) ps[e] += __shfl_xor(ps[e], m);
    }
    if (l15 == 0) {
#pragma unroll
      for (int e = 0; e < 4; ++e)
        part[wid][mf * 16 + lg * 4 + e] = ps[e];
    }
  }
  __syncthreads();
  if (tid < 128) {
    float tot = b3[0];
#pragma unroll
    for (int w = 0; w < 8; ++w) tot += part[w][tid];
    float sg = 1.f / (1.f + expf(-tot));
    int i = bi * 8 + (tid >> 4);
    int j = bj * 16 + (tid & 15);
    if (i < j) {
      edges[i * NN + j] = sg;
      edges[j * NN + i] = sg;
    } else if (i == j) {
      edges[i * NN + i] = 0.f;
    }
  }
}

extern "C" void kernel_launch(void* const* d_in, const int* in_sizes, int n_in,
                              void* d_out, int out_size, void* d_ws, size_t ws_size,
                              hipStream_t stream) {
  const float* node = (const float*)d_in[0];
  const float* adj  = (const float*)d_in[1];
  const float* g1wl = (const float*)d_in[2];
  const float* g1bl = (const float*)d_in[3];
  const float* g1ws = (const float*)d_in[4];
  const float* g1bs = (const float*)d_in[5];
  const float* g2wl = (const float*)d_in[6];
  const float* g2bl = (const float*)d_in[7];
  const float* g2ws = (const float*)d_in[8];
  const float* g2bs = (const float*)d_in[9];
  const float* g3wl = (const float*)d_in[10];
  const float* g3bl = (const float*)d_in[11];
  const float* g3ws = (const float*)d_in[12];
  const float* g3bs = (const float*)d_in[13];
  const float* w1 = (const float*)d_in[14];
  const float* b1 = (const float*)d_in[15];
  const float* w2 = (const float*)d_in[16];
  const float* b2 = (const float*)d_in[17];
  const float* w3 = (const float*)d_in[18];
  const float* b3 = (const float*)d_in[19];

  float* out = (float*)d_out;
  float* emb = out;                 // [512][256]
  float* edges = out + NN * FF;     // [512][512]

  char* wsb = (char*)d_ws;
  float* adjn = (float*)wsb;                     // 1 MB
  float* Tb   = (float*)(wsb + (1u << 20));      // 1 MB
  float* Sb   = (float*)(wsb + (2u << 20));      // 1 MB
  float* xa   = (float*)(wsb + (3u << 20));      // 1 MB
  float* xb   = (float*)(wsb + (4u << 20));      // 1 MB
  ushort* w2t2 = (ushort*)(wsb + (5u << 20));    // 512 KB
  float* Amat = Tb;  // reused after GCN
  float* Bmat = Sb;

  // ---- P1: gemm1 (T/S = node@g1 + bias) + rownorm + w2 pack, one launch
  prep_gemm1<<<1152, 256, 0, stream>>>(adj, adjn, w2, w2t2, node,
                                       g1wl, g1bl, g1ws, g1bs, Tb, Sb);
  // ---- P2: xa = relu(adjn @ Tb + Sb)   (4-way K-split, 1024 thr)
  gemm_ks4<true><<<dim3(8, 32, 1), 1024, 0, stream>>>(
      NN, adjn, NN, Tb, Tb, HH, nullptr, nullptr,
      Sb, Sb, HH, xa, xa, HH);
  // ---- P3: layer-2 T/S = xa @ g2 + bias
  gemm_ks<false><<<dim3(8, 32, 2), 512, 0, stream>>>(
      HH, xa, HH, g2wl, g2ws, HH, g2bl, g2bs,
      nullptr, nullptr, 0, Tb, Sb, HH);
  // ---- P4: xb = relu(adjn @ Tb + Sb)
  gemm_ks4<true><<<dim3(8, 32, 1), 1024, 0, stream>>>(
      NN, adjn, NN, Tb, Tb, HH, nullptr, nullptr,
      Sb, Sb, HH, xb, xb, HH);
  // ---- P5: layer-3 T/S = xb @ g3 + bias  (N=256; full GPU at 4 waves/SIMD)
  gemm_ks4<false><<<dim3(4, 32, 2), 1024, 0, stream>>>(
      HH, xb, HH, g3wl, g3ws, FF, g3bl, g3bs,
      nullptr, nullptr, 0, Tb, Sb, FF);
  // ---- P6: emb = adjn @ Tb + Sb (no relu)  (4-way K-split)
  gemm_ks4<false><<<dim3(4, 32, 1), 1024, 0, stream>>>(
      NN, adjn, NN, Tb, Tb, FF, nullptr, nullptr,
      Sb, Sb, FF, emb, emb, FF);
  // ---- P7: Amat = emb@w1_top + b1, Bmat = emb@w1_bot
  gemm_ks<false><<<dim3(8, 32, 2), 512, 0, stream>>>(
      FF, emb, FF, w1, w1 + FF * HH, HH, b1, nullptr,
      nullptr, nullptr, 0, Amat, Bmat, HH);

  // ---- P8: fused edge MLP, exact triangular grid (32^2 + 32 = 1056 tiles)
  edge_mlp<<<1056, 512, 0, stream>>>(Amat, Bmat, w2t2, b2, w3, b3, edges);
}

// Round 17
// 166.180 us; speedup vs baseline: 2.0519x; 2.0519x over previous
//
#include <hip/hip_runtime.h>
#include <hip/hip_bf16.h>

// GraphNeuralAssociator: GCN(3 layers, fp32) + all-pairs edge MLP.
// Edge MLP layer 1 factorized: h1(i,j) = relu(Amat[i] + Bmat[j]).
// Layer 2 (68.6 GF) = bf16 MFMA 16x16x32, fp32 accum; layer 3 + sigmoid fused.
// v17: REVERT v16's edge changes (parity-staggered build extended acc live
// ranges across a divergent region -> 369 MB scratch spill, 96->271us; the
// v9 straight-line schedule is load-bearing at acc=128/256-reg budget).
// Edge = v15/v9 verbatim. KEEP v16 chain (P5/P6 on gemm_ks4 z-dual).

#define NN 512
#define FF 256
#define HH 512

typedef __attribute__((ext_vector_type(8))) short s8v;   // 8 x bf16 bits
typedef __attribute__((ext_vector_type(4))) float f4v;   // MFMA acc

__device__ __forceinline__ ushort f2bf(float f) {
  unsigned u = __float_as_uint(f);
  unsigned r = (u + 0x7fffu + ((u >> 16) & 1u)) >> 16;
  return (ushort)r;
}

// ---------------- device tile GEMM: 16x64 tile, BK=64 (256 thr) ------------
template <bool RELU>
__device__ __forceinline__ void gemm_tile64(
    int m0, int n0, int K,
    const float* __restrict__ A, int lda,
    const float* __restrict__ B, int ldb,
    const float* __restrict__ bias,
    const float* __restrict__ add, int ldadd,
    float* __restrict__ C, int ldc, int tid)
{
  __shared__ float As[64][18];  // [k][m]
  __shared__ float Bs[64][68];  // [k][n]
  float4 acc = {0.f, 0.f, 0.f, 0.f};
  const int ty = tid >> 4, tx = tid & 15;

  const int am = tid >> 4;      // A row 0..15
  const int ak = tid & 15;      // k float4 index (16 x 4 = 64 k)
  const int bk = tid >> 4;      // B rows bk + 16r, r=0..3
  const int bn = tid & 15;      // col float4 index

  float4 pa = *(const float4*)&A[(m0 + am) * lda + ak * 4];
  float4 pb0 = *(const float4*)&B[bk * ldb + n0 + bn * 4];
  float4 pb1 = *(const float4*)&B[(bk + 16) * ldb + n0 + bn * 4];
  float4 pb2 = *(const float4*)&B[(bk + 32) * ldb + n0 + bn * 4];
  float4 pb3 = *(const float4*)&B[(bk + 48) * ldb + n0 + bn * 4];

  for (int k0 = 0; k0 < K; k0 += 64) {
    As[ak * 4 + 0][am] = pa.x;
    As[ak * 4 + 1][am] = pa.y;
    As[ak * 4 + 2][am] = pa.z;
    As[ak * 4 + 3][am] = pa.w;
    *(float4*)&Bs[bk][bn * 4] = pb0;
    *(float4*)&Bs[bk + 16][bn * 4] = pb1;
    *(float4*)&Bs[bk + 32][bn * 4] = pb2;
    *(float4*)&Bs[bk + 48][bn * 4] = pb3;
    __syncthreads();
    if (k0 + 64 < K) {
      pa = *(const float4*)&A[(m0 + am) * lda + k0 + 64 + ak * 4];
      pb0 = *(const float4*)&B[(k0 + 64 + bk) * ldb + n0 + bn * 4];
      pb1 = *(const float4*)&B[(k0 + 80 + bk) * ldb + n0 + bn * 4];
      pb2 = *(const float4*)&B[(k0 + 96 + bk) * ldb + n0 + bn * 4];
      pb3 = *(const float4*)&B[(k0 + 112 + bk) * ldb + n0 + bn * 4];
    }
#pragma unroll
    for (int k = 0; k < 64; ++k) {
      float a = As[k][ty];
      float4 b = *(const float4*)&Bs[k][tx * 4];
      acc.x += a * b.x; acc.y += a * b.y; acc.z += a * b.z; acc.w += a * b.w;
    }
    __syncthreads();
  }

  int m = m0 + ty;
  float4 v = acc;
  if (bias) {
    float4 bv = *(const float4*)&bias[n0 + tx * 4];
    v.x += bv.x; v.y += bv.y; v.z += bv.z; v.w += bv.w;
  }
  if (add) {
    float4 d = *(const float4*)&add[m * ldadd + n0 + tx * 4];
    v.x += d.x; v.y += d.y; v.z += d.z; v.w += d.w;
  }
  if (RELU) {
    v.x = fmaxf(v.x, 0.f); v.y = fmaxf(v.y, 0.f);
    v.z = fmaxf(v.z, 0.f); v.w = fmaxf(v.w, 0.f);
  }
  *(float4*)&C[m * ldc + n0 + tx * 4] = v;
}

// ---------------- K-split GEMM: 512 thr, 16x64 tile, halves split K --------
template <bool RELU>
__global__ __launch_bounds__(512)
void gemm_ks(int K,
             const float* __restrict__ A, int lda,
             const float* __restrict__ B0, const float* __restrict__ B1, int ldb,
             const float* __restrict__ bias0, const float* __restrict__ bias1,
             const float* __restrict__ add0, const float* __restrict__ add1, int ldadd,
             float* __restrict__ C0, float* __restrict__ C1, int ldc)
{
  const float* B = blockIdx.z ? B1 : B0;
  const float* bias = blockIdx.z ? bias1 : bias0;
  const float* add = blockIdx.z ? add1 : add0;
  float* C = blockIdx.z ? C1 : C0;
  const int n0 = blockIdx.x * 64;
  const int m0 = blockIdx.y * 16;
  const int tid = threadIdx.x;
  const int half = tid >> 8;
  const int t = tid & 255;
  const int ty = t >> 4, tx = t & 15;

  __shared__ float As[2][64][18];
  __shared__ float Bs[2][64][68];
  __shared__ float red[16][68];

  float4 acc = {0.f, 0.f, 0.f, 0.f};
  const int am = t >> 4, ak = t & 15;
  const int bk = t >> 4, bn = t & 15;
  const int Kh = K >> 1;
  const int kb = half * Kh;

  float4 pa = *(const float4*)&A[(m0 + am) * lda + kb + ak * 4];
  float4 pb0 = *(const float4*)&B[(kb + bk) * ldb + n0 + bn * 4];
  float4 pb1 = *(const float4*)&B[(kb + bk + 16) * ldb + n0 + bn * 4];
  float4 pb2 = *(const float4*)&B[(kb + bk + 32) * ldb + n0 + bn * 4];
  float4 pb3 = *(const float4*)&B[(kb + bk + 48) * ldb + n0 + bn * 4];

  for (int k0 = 0; k0 < Kh; k0 += 64) {
    As[half][ak * 4 + 0][am] = pa.x;
    As[half][ak * 4 + 1][am] = pa.y;
    As[half][ak * 4 + 2][am] = pa.z;
    As[half][ak * 4 + 3][am] = pa.w;
    *(float4*)&Bs[half][bk][bn * 4] = pb0;
    *(float4*)&Bs[half][bk + 16][bn * 4] = pb1;
    *(float4*)&Bs[half][bk + 32][bn * 4] = pb2;
    *(float4*)&Bs[half][bk + 48][bn * 4] = pb3;
    __syncthreads();
    if (k0 + 64 < Kh) {
      pa = *(const float4*)&A[(m0 + am) * lda + kb + k0 + 64 + ak * 4];
      pb0 = *(const float4*)&B[(kb + k0 + 64 + bk) * ldb + n0 + bn * 4];
      pb1 = *(const float4*)&B[(kb + k0 + 80 + bk) * ldb + n0 + bn * 4];
      pb2 = *(const float4*)&B[(kb + k0 + 96 + bk) * ldb + n0 + bn * 4];
      pb3 = *(const float4*)&B[(kb + k0 + 112 + bk) * ldb + n0 + bn * 4];
    }
#pragma unroll
    for (int k = 0; k < 64; ++k) {
      float a = As[half][k][ty];
      float4 b = *(const float4*)&Bs[half][k][tx * 4];
      acc.x += a * b.x; acc.y += a * b.y; acc.z += a * b.z; acc.w += a * b.w;
    }
    __syncthreads();
  }

  if (half) *(float4*)&red[ty][tx * 4] = acc;
  __syncthreads();
  if (!half) {
    float4 r = *(const float4*)&red[ty][tx * 4];
    float4 v = acc;
    v.x += r.x; v.y += r.y; v.z += r.z; v.w += r.w;
    int m = m0 + ty;
    if (bias) {
      float4 bv = *(const float4*)&bias[n0 + tx * 4];
      v.x += bv.x; v.y += bv.y; v.z += bv.z; v.w += bv.w;
    }
    if (add) {
      float4 d = *(const float4*)&add[m * ldadd + n0 + tx * 4];
      v.x += d.x; v.y += d.y; v.z += d.z; v.w += d.w;
    }
    if (RELU) {
      v.x = fmaxf(v.x, 0.f); v.y = fmaxf(v.y, 0.f);
      v.z = fmaxf(v.z, 0.f); v.w = fmaxf(v.w, 0.f);
    }
    *(float4*)&C[m * ldc + n0 + tx * 4] = v;
  }
}

// ---------------- 4-way K-split GEMM: 1024 thr, 16x64 tile, z-dual ---------
template <bool RELU>
__global__ __launch_bounds__(1024)
void gemm_ks4(int K,
              const float* __restrict__ A, int lda,
              const float* __restrict__ B0, const float* __restrict__ B1, int ldb,
              const float* __restrict__ bias0, const float* __restrict__ bias1,
              const float* __restrict__ add0, const float* __restrict__ add1, int ldadd,
              float* __restrict__ C0, float* __restrict__ C1, int ldc)
{
  const float* B = blockIdx.z ? B1 : B0;
  const float* bias = blockIdx.z ? bias1 : bias0;
  const float* add = blockIdx.z ? add1 : add0;
  float* C = blockIdx.z ? C1 : C0;
  const int n0 = blockIdx.x * 64;
  const int m0 = blockIdx.y * 16;
  const int tid = threadIdx.x;
  const int q = tid >> 8;         // 0..3
  const int t = tid & 255;
  const int ty = t >> 4, tx = t & 15;

  __shared__ float As[4][64][18];   // 18.0 KB
  __shared__ float Bs[4][64][68];   // 68.0 KB
  __shared__ float red[3][16][68];  // 12.75 KB

  float4 acc = {0.f, 0.f, 0.f, 0.f};
  const int am = ty, ak = tx;
  const int bk = ty, bn = tx;
  const int Kq = K >> 2;
  const int kb = q * Kq;

  float4 pa = *(const float4*)&A[(m0 + am) * lda + kb + ak * 4];
  float4 pb0 = *(const float4*)&B[(kb + bk) * ldb + n0 + bn * 4];
  float4 pb1 = *(const float4*)&B[(kb + bk + 16) * ldb + n0 + bn * 4];
  float4 pb2 = *(const float4*)&B[(kb + bk + 32) * ldb + n0 + bn * 4];
  float4 pb3 = *(const float4*)&B[(kb + bk + 48) * ldb + n0 + bn * 4];

  for (int k0 = 0; k0 < Kq; k0 += 64) {
    As[q][ak * 4 + 0][am] = pa.x;
    As[q][ak * 4 + 1][am] = pa.y;
    As[q][ak * 4 + 2][am] = pa.z;
    As[q][ak * 4 + 3][am] = pa.w;
    *(float4*)&Bs[q][bk][bn * 4] = pb0;
    *(float4*)&Bs[q][bk + 16][bn * 4] = pb1;
    *(float4*)&Bs[q][bk + 32][bn * 4] = pb2;
    *(float4*)&Bs[q][bk + 48][bn * 4] = pb3;
    __syncthreads();
    if (k0 + 64 < Kq) {
      pa = *(const float4*)&A[(m0 + am) * lda + kb + k0 + 64 + ak * 4];
      pb0 = *(const float4*)&B[(kb + k0 + 64 + bk) * ldb + n0 + bn * 4];
      pb1 = *(const float4*)&B[(kb + k0 + 80 + bk) * ldb + n0 + bn * 4];
      pb2 = *(const float4*)&B[(kb + k0 + 96 + bk) * ldb + n0 + bn * 4];
      pb3 = *(const float4*)&B[(kb + k0 + 112 + bk) * ldb + n0 + bn * 4];
    }
#pragma unroll
    for (int k = 0; k < 64; ++k) {
      float a = As[q][k][ty];
      float4 b = *(const float4*)&Bs[q][k][tx * 4];
      acc.x += a * b.x; acc.y += a * b.y; acc.z += a * b.z; acc.w += a * b.w;
    }
    __syncthreads();
  }

  if (q) *(float4*)&red[q - 1][ty][tx * 4] = acc;
  __syncthreads();
  if (!q) {
    float4 v = acc;
#pragma unroll
    for (int r = 0; r < 3; ++r) {
      float4 p = *(const float4*)&red[r][ty][tx * 4];
      v.x += p.x; v.y += p.y; v.z += p.z; v.w += p.w;
    }
    int m = m0 + ty;
    if (bias) {
      float4 bv = *(const float4*)&bias[n0 + tx * 4];
      v.x += bv.x; v.y += bv.y; v.z += bv.z; v.w += bv.w;
    }
    if (add) {
      float4 d = *(const float4*)&add[m * ldadd + n0 + tx * 4];
      v.x += d.x; v.y += d.y; v.z += d.z; v.w += d.w;
    }
    if (RELU) {
      v.x = fmaxf(v.x, 0.f); v.y = fmaxf(v.y, 0.f);
      v.z = fmaxf(v.z, 0.f); v.w = fmaxf(v.w, 0.f);
    }
    *(float4*)&C[m * ldc + n0 + tx * 4] = v;
  }
}

// ---------------- launch 1: gemm1 (blocks 0..511) + rownorm (512..1023)
//                  + w2 pack (1024..1151) -----------------------------------
__global__ __launch_bounds__(256)
void prep_gemm1(const float* __restrict__ adj, float* __restrict__ adjn,
                const float* __restrict__ w2, ushort* __restrict__ w2t2,
                const float* __restrict__ node,
                const float* __restrict__ g1wl, const float* __restrict__ g1bl,
                const float* __restrict__ g1ws, const float* __restrict__ g1bs,
                float* __restrict__ Tb, float* __restrict__ Sb) {
  int b = blockIdx.x;
  int tid = threadIdx.x;
  if (b < 512) {
    int z = b >> 8, t = b & 255;
    int m0 = (t >> 3) * 16, n0 = (t & 7) * 64;
    gemm_tile64<false>(m0, n0, FF, node, FF, z ? g1ws : g1wl, HH,
                       z ? g1bs : g1bl, nullptr, 0, z ? Sb : Tb, HH, tid);
  } else if (b < 1024) {
    int row = b - 512;
    const float* r = adj + row * NN;
    float a0 = r[tid], a1 = r[tid + 256];
    float s = a0 + a1;
#pragma unroll
    for (int m = 1; m < 64; m <<= 1) s += __shfl_xor(s, m);
    __shared__ float wsum[4];
    if ((tid & 63) == 0) wsum[tid >> 6] = s;
    __syncthreads();
    float inv = 1.f / (wsum[0] + wsum[1] + wsum[2] + wsum[3] + 1e-8f);
    float* o = adjn + row * NN;
    o[tid] = a0 * inv;
    o[tid + 256] = a1 * inv;
  } else {
    // w2 -> bf16 pack: w2t2[(k>>5)*16384 + col*32 + (k&31)]
    int b2 = b - 1024;                      // 0..127
    int slab = b2 >> 3;                     // 16 slabs of 32 k
    int col = (b2 & 7) * 64 + (tid >> 2);
    int kq = tid & 3;                       // 8-k sub-block
    int k0 = slab * 32 + kq * 8;
    ushort tmp[8];
#pragma unroll
    for (int e = 0; e < 8; ++e) tmp[e] = f2bf(w2[(k0 + e) * HH + col]);
    ushort* dst = w2t2 + slab * 16384 + col * 32 + kq * 8;
    *(ushort4*)dst = *(ushort4*)tmp;
    *(ushort4*)(dst + 4) = *(ushort4*)&tmp[4];
  }
}

// ---------------- fused edge MLP (v9/v15 verbatim) ----------------
__global__ __launch_bounds__(512)
__attribute__((amdgpu_waves_per_eu(2, 2)))
void edge_mlp(const float* __restrict__ Amat, const float* __restrict__ Bmat,
              const ushort* __restrict__ w2t2,
              const float* __restrict__ b2, const float* __restrict__ w3,
              const float* __restrict__ b3,
              float* __restrict__ edges)
{
  __shared__ ushort h1s[2][128 * 128];   // 64 KB
  __shared__ float rowsv[2][24][128];    // 24 KB: rows 0-7 = A, 8-23 = B
  __shared__ float part[8][128];         // 4 KB

  // exact upper-triangle tile decode: tiles before col-block bj = bj^2+bj
  const int tb = (int)blockIdx.x;
  int bj = (int)((sqrtf(4.f * tb + 1.f) - 1.f) * 0.5f);
  while (bj * bj + bj > tb) --bj;
  while ((bj + 1) * (bj + 2) <= tb) ++bj;
  const int bi = tb - bj * bj - bj;

  const int tid = threadIdx.x;
  const int wid = tid >> 6;
  const int lane = tid & 63;
  const int l15 = lane & 15;
  const int lg = lane >> 4;

  const f4v zero = {0.f, 0.f, 0.f, 0.f};
  f4v acc[8][4];
#pragma unroll
  for (int mf = 0; mf < 8; ++mf)
#pragma unroll
    for (int nf = 0; nf < 4; ++nf) acc[mf][nf] = zero;

  // ---- row staging: 24 rows x 128 floats per chunk = 768 float4 elems ----
  const int r1 = tid >> 5, kc1 = tid & 31;          // elem tid (all threads)
  const int r2 = 16 + (tid >> 5);                   // elem 512+tid (tid<256)
  const float* src1base = (r1 < 8) ? (Amat + (bi * 8 + r1) * HH)
                                   : (Bmat + (bj * 16 + r1 - 8) * HH);
  const float* src2base = Bmat + (bj * 16 + r2 - 8) * HH;  // rows 16..23

  float4 ra, rb;
  auto issue_rows = [&](int ch) {  // global loads only (tiny: 1.5 f4/thread)
    ra = *(const float4*)(src1base + ch * 128 + kc1 * 4);
    if (tid < 256) rb = *(const float4*)(src2base + ch * 128 + kc1 * 4);
  };
  auto write_rows = [&](int buf) {  // ds_write (waits on the row loads)
    *(float4*)&rowsv[buf][r1][kc1 * 4] = ra;
    if (tid < 256) *(float4*)&rowsv[buf][r2][kc1 * 4] = rb;
  };
  // build h1 chunk from staged rows: h1[p][k]=relu(Arow[i(p)]+Brow[j(p)]) bf16
  auto build_h1 = [&](int buf) {
#pragma unroll
    for (int q = 0; q < 8; ++q) {
      int fidx = q * 512 + tid;
      int p = fidx >> 5;        // pair row 0..127
      int k4 = fidx & 31;       // float4 index within 128-k chunk
      float4 av = *(const float4*)&rowsv[buf][p >> 4][k4 * 4];
      float4 bv = *(const float4*)&rowsv[buf][8 + (p & 15)][k4 * 4];
      ushort4 pk;
      pk.x = f2bf(fmaxf(av.x + bv.x, 0.f));
      pk.y = f2bf(fmaxf(av.y + bv.y, 0.f));
      pk.z = f2bf(fmaxf(av.z + bv.z, 0.f));
      pk.w = f2bf(fmaxf(av.w + bv.w, 0.f));
      int off = (p * 256 + k4 * 8) ^ ((p & 7) << 4);
      *(ushort4*)((char*)h1s[buf] + off) = pk;
    }
  };

  // lgkm-only barrier (no vmcnt drain; w2/row prefetch stays in flight)
  auto lgkm_barrier = [] {
    asm volatile("s_waitcnt lgkmcnt(0)" ::: "memory");
    __builtin_amdgcn_s_barrier();
  };

  // prologue: stage rows(0) -> rowsv[0], build h1s[0]
  issue_rows(0);
  write_rows(0);
  lgkm_barrier();           // rows visible block-wide
  build_h1(0);
  lgkm_barrier();           // h1s[0] ready

  // wave's w2 base: cols [64*wid ..), lane l15 col, lane-group lg k-offset
  const ushort* wbase = w2t2 + wid * 2048 + l15 * 32 + lg * 8;

  // rolling w2 prefetch (one 32-k slab ahead, across chunk boundaries)
  s8v nb0, nb1, nb2, nb3;
  nb0 = *(const s8v*)wbase;
  nb1 = *(const s8v*)(wbase + 512);
  nb2 = *(const s8v*)(wbase + 1024);
  nb3 = *(const s8v*)(wbase + 1536);

  // one 32-k slab: 8 ds_reads + 32 MFMAs, rolls w2 prefetch
  auto slab_step = [&](int cur, int slab) {
    s8v cb0 = nb0, cb1 = nb1, cb2 = nb2, cb3 = nb3;
    if (slab < 15) {
      const ushort* wb = wbase + (slab + 1) * 16384;
      nb0 = *(const s8v*)wb;
      nb1 = *(const s8v*)(wb + 512);
      nb2 = *(const s8v*)(wb + 1024);
      nb3 = *(const s8v*)(wb + 1536);
    }
    int ks = slab & 3;
    __builtin_amdgcn_s_setprio(1);
#pragma unroll
    for (int mf = 0; mf < 8; ++mf) {
      int p = mf * 16 + l15;
      int off = (p * 256 + ks * 64 + lg * 16) ^ ((p & 7) << 4);
      s8v a = *(const s8v*)((const char*)h1s[cur] + off);
      acc[mf][0] = __builtin_amdgcn_mfma_f32_16x16x32_bf16(a, cb0, acc[mf][0], 0, 0, 0);
      acc[mf][1] = __builtin_amdgcn_mfma_f32_16x16x32_bf16(a, cb1, acc[mf][1], 0, 0, 0);
      acc[mf][2] = __builtin_amdgcn_mfma_f32_16x16x32_bf16(a, cb2, acc[mf][2], 0, 0, 0);
      acc[mf][3] = __builtin_amdgcn_mfma_f32_16x16x32_bf16(a, cb3, acc[mf][3], 0, 0, 0);
    }
    __builtin_amdgcn_s_setprio(0);
  };

#pragma unroll
  for (int ch = 0; ch < 4; ++ch) {
    int cur = ch & 1;
    if (ch < 3) issue_rows(ch + 1);          // row loads fly under slabs 0-1
    slab_step(cur, ch * 4 + 0);
    slab_step(cur, ch * 4 + 1);
    if (ch < 3) write_rows(cur ^ 1);         // counted vmcnt (w2 loads younger)
    slab_step(cur, ch * 4 + 2);
    if (ch < 3) lgkm_barrier();              // rows visible block-wide
    slab_step(cur, ch * 4 + 3);
    if (ch < 3) {
      build_h1(cur ^ 1);                     // LDS->VALU->LDS
      lgkm_barrier();                        // h1s[cur^1] ready
    }
  }

  // epilogue: h2 = relu(acc+b2); partial = h2 . w3 over this wave's 64 cols
  float bb[4], ww[4];
#pragma unroll
  for (int nf = 0; nf < 4; ++nf) {
    int col = wid * 64 + nf * 16 + l15;
    bb[nf] = b2[col];
    ww[nf] = w3[col];
  }
#pragma unroll
  for (int mf = 0; mf < 8; ++mf) {
    float ps[4];
#pragma unroll
    for (int e = 0; e < 4; ++e) {
      ps[e] = fmaxf(acc[mf][0][e] + bb[0], 0.f) * ww[0] +
              fmaxf(acc[mf][1][e] + bb[1], 0.f) * ww[1] +
              fmaxf(acc[mf][2][e] + bb[2], 0.f) * ww[2] +
              fmaxf(acc[mf][3][e] + bb[3], 0.f) * ww[3];
    }
#pragma unroll
    for (int m = 1; m < 16; m <<= 1) {
#pragma unroll
      for (int e = 0; e < 4; ++e) ps[e] += __shfl_xor(ps[e], m);
    }
    if (l15 == 0) {
#pragma unroll
      for (int e = 0; e < 4; ++e)
        part[wid][mf * 16 + lg * 4 + e] = ps[e];
    }
  }
  __syncthreads();
  if (tid < 128) {
    float tot = b3[0];
#pragma unroll
    for (int w = 0; w < 8; ++w) tot += part[w][tid];
    float sg = 1.f / (1.f + expf(-tot));
    int i = bi * 8 + (tid >> 4);
    int j = bj * 16 + (tid & 15);
    if (i < j) {
      edges[i * NN + j] = sg;
      edges[j * NN + i] = sg;
    } else if (i == j) {
      edges[i * NN + i] = 0.f;
    }
  }
}

extern "C" void kernel_launch(void* const* d_in, const int* in_sizes, int n_in,
                              void* d_out, int out_size, void* d_ws, size_t ws_size,
                              hipStream_t stream) {
  const float* node = (const float*)d_in[0];
  const float* adj  = (const float*)d_in[1];
  const float* g1wl = (const float*)d_in[2];
  const float* g1bl = (const float*)d_in[3];
  const float* g1ws = (const float*)d_in[4];
  const float* g1bs = (const float*)d_in[5];
  const float* g2wl = (const float*)d_in[6];
  const float* g2bl = (const float*)d_in[7];
  const float* g2ws = (const float*)d_in[8];
  const float* g2bs = (const float*)d_in[9];
  const float* g3wl = (const float*)d_in[10];
  const float* g3bl = (const float*)d_in[11];
  const float* g3ws = (const float*)d_in[12];
  const float* g3bs = (const float*)d_in[13];
  const float* w1 = (const float*)d_in[14];
  const float* b1 = (const float*)d_in[15];
  const float* w2 = (const float*)d_in[16];
  const float* b2 = (const float*)d_in[17];
  const float* w3 = (const float*)d_in[18];
  const float* b3 = (const float*)d_in[19];

  float* out = (float*)d_out;
  float* emb = out;                 // [512][256]
  float* edges = out + NN * FF;     // [512][512]

  char* wsb = (char*)d_ws;
  float* adjn = (float*)wsb;                     // 1 MB
  float* Tb   = (float*)(wsb + (1u << 20));      // 1 MB
  float* Sb   = (float*)(wsb + (2u << 20));      // 1 MB
  float* xa   = (float*)(wsb + (3u << 20));      // 1 MB
  float* xb   = (float*)(wsb + (4u << 20));      // 1 MB
  ushort* w2t2 = (ushort*)(wsb + (5u << 20));    // 512 KB
  float* Amat = Tb;  // reused after GCN
  float* Bmat = Sb;

  // ---- P1: gemm1 (T/S = node@g1 + bias) + rownorm + w2 pack, one launch
  prep_gemm1<<<1152, 256, 0, stream>>>(adj, adjn, w2, w2t2, node,
                                       g1wl, g1bl, g1ws, g1bs, Tb, Sb);
  // ---- P2: xa = relu(adjn @ Tb + Sb)   (4-way K-split, 1024 thr)
  gemm_ks4<true><<<dim3(8, 32, 1), 1024, 0, stream>>>(
      NN, adjn, NN, Tb, Tb, HH, nullptr, nullptr,
      Sb, Sb, HH, xa, xa, HH);
  // ---- P3: layer-2 T/S = xa @ g2 + bias
  gemm_ks<false><<<dim3(8, 32, 2), 512, 0, stream>>>(
      HH, xa, HH, g2wl, g2ws, HH, g2bl, g2bs,
      nullptr, nullptr, 0, Tb, Sb, HH);
  // ---- P4: xb = relu(adjn @ Tb + Sb)
  gemm_ks4<true><<<dim3(8, 32, 1), 1024, 0, stream>>>(
      NN, adjn, NN, Tb, Tb, HH, nullptr, nullptr,
      Sb, Sb, HH, xb, xb, HH);
  // ---- P5: layer-3 T/S = xb @ g3 + bias  (N=256; full GPU at 4 waves/SIMD)
  gemm_ks4<false><<<dim3(4, 32, 2), 1024, 0, stream>>>(
      HH, xb, HH, g3wl, g3ws, FF, g3bl, g3bs,
      nullptr, nullptr, 0, Tb, Sb, FF);
  // ---- P6: emb = adjn @ Tb + Sb (no relu)  (4-way K-split)
  gemm_ks4<false><<<dim3(4, 32, 1), 1024, 0, stream>>>(
      NN, adjn, NN, Tb, Tb, FF, nullptr, nullptr,
      Sb, Sb, FF, emb, emb, FF);
  // ---- P7: Amat = emb@w1_top + b1, Bmat = emb@w1_bot
  gemm_ks<false><<<dim3(8, 32, 2), 512, 0, stream>>>(
      FF, emb, FF, w1, w1 + FF * HH, HH, b1, nullptr,
      nullptr, nullptr, 0, Amat, Bmat, HH);

  // ---- P8: fused edge MLP, exact triangular grid (32^2 + 32 = 1056 tiles)
  edge_mlp<<<1056, 512, 0, stream>>>(Amat, Bmat, w2t2, b2, w3, b3, edges);
}